// Round 14
// baseline (102.780 us; speedup 1.0000x reference)
//
#include <hip/hip_runtime.h>
#include <hip/hip_fp16.h>

// SpMM scatter-reduce: out[r] = sum_{e: rows[e]==r} vals[e] * embeds[cols[e]]
// TWO-KERNEL pipeline (no global scan, no global atomics):
//   A) build_convert (partitioned grid, 512 thr):
//      blocks [0,NWG): chunk-local counting sort. Per WG: LDS histogram of its
//      6250-edge chunk over 1563 buckets -> LDS scan -> write per-chunk bucket
//      starts into TRANSPOSED matT[b][w] -> scatter edges bucket-grouped into
//      buf1 within the chunk's window [w*CHUNK, (w+1)*CHUNK).
//      blocks [NWG,..): embeds fp32 -> fp16.
//   B) finalize_spmm (256 thr, one WG per bucket; 1563 WGs ~ all co-resident
//      at 8 WG/CU): thread t owns chunk t's sub-run (avg ~4 contiguous edges).
//      Bounds = two coalesced 1KB rows of matT. Pass1 count rows -> scan(64)
//      -> pass2 scatter into row-sorted LDS sedge (packed u32: fp16val<<17|col)
//      -> row-parallel spmm: 8 groups x 32 lanes, 8 rows/group, lane = half2
//      feature pair, x8 gather ILP.

#define N_NODES 100000
#define N_EDGES 1600000
#define D_FEAT  48

#define RPB 64
#define NBUCKETS ((N_NODES + RPB - 1) / RPB)                    // 1563
#define NWG 256
#define CHUNK (N_EDGES / NWG)                                   // 6250 (exact)
#define MROW (NBUCKETS + 1)                                     // 1564 rows in matT
#define CONV_N4 ((N_NODES * D_FEAT) / 4)                        // 1200000
#define CONV_BLK ((CONV_N4 + 511) / 512)                        // 2344
#define CAP 1536   // bucket mean 1024, sd ~32 -> 16 sigma headroom

// ---- A) fused chunk-local counting sort + embeds fp32 -> fp16 ----
__global__ __launch_bounds__(512) void build_convert(const int* __restrict__ rows,
                                                     const int* __restrict__ cols,
                                                     const float* __restrict__ vals,
                                                     unsigned int* __restrict__ matT,
                                                     int2* __restrict__ buf1,
                                                     const float4* __restrict__ esrc,
                                                     __half2* __restrict__ edst) {
    const int t = threadIdx.x;
    if (blockIdx.x < NWG) {
        __shared__ unsigned int hist[NBUCKETS];   // counts -> cursors
        __shared__ unsigned int part[512];
        const int w = blockIdx.x;
        for (int i = t; i < NBUCKETS; i += 512) hist[i] = 0u;
        __syncthreads();
        const int lo = w * CHUNK, hi = lo + CHUNK;
        for (int e = lo + t; e < hi; e += 512)
            atomicAdd(&hist[((unsigned)rows[e]) >> 6], 1u);
        __syncthreads();
        // scan 1563 entries: thread t owns [t*4, t*4+4)
        unsigned int c[4], sum = 0;
#pragma unroll
        for (int k = 0; k < 4; ++k) {
            int idx = t * 4 + k;
            c[k] = (idx < NBUCKETS) ? hist[idx] : 0u;
            sum += c[k];
        }
        part[t] = sum;
        __syncthreads();
        for (int off = 1; off < 512; off <<= 1) {
            unsigned int u = (t >= off) ? part[t - off] : 0u;
            __syncthreads();
            part[t] += u;
            __syncthreads();
        }
        unsigned int pre = (t == 0) ? 0u : part[t - 1];
#pragma unroll
        for (int k = 0; k < 4; ++k) {
            int idx = t * 4 + k;
            if (idx < NBUCKETS) {
                matT[(size_t)idx * NWG + w] = pre;   // chunk-local bucket start
                hist[idx] = pre;                     // reuse as cursor
                pre += c[k];
            }
        }
        if (t == 0) matT[(size_t)NBUCKETS * NWG + w] = CHUNK;  // sentinel
        __syncthreads();
        for (int e = lo + t; e < hi; e += 512) {
            unsigned r = (unsigned)rows[e];
            unsigned b = r >> 6;
            unsigned pos = (unsigned)lo + atomicAdd(&hist[b], 1u);  // LDS atomic
            // pack: bits[22:17] = local row (r & 63), bits[16:0] = col (< 2^17)
            buf1[pos] = make_int2((int)(((r & 63u) << 17) | (unsigned)cols[e]),
                                  __float_as_int(vals[e]));
        }
    } else {
        int i = (blockIdx.x - NWG) * 512 + t;
        if (i < CONV_N4) {
            float4 v = esrc[i];
            edst[2 * i]     = __floats2half2_rn(v.x, v.y);
            edst[2 * i + 1] = __floats2half2_rn(v.z, v.w);
        }
    }
}

// ---- B) per-bucket gather from sub-runs + row-sort + fp16 spmm ----
__global__ __launch_bounds__(256) void finalize_spmm(const unsigned int* __restrict__ matT,
                                                     const int2* __restrict__ buf1,
                                                     const __half2* __restrict__ embeds_h2,
                                                     float* __restrict__ out) {
    __shared__ unsigned int sedge[CAP];          // (fp16val<<17)|col, row-sorted
    __shared__ unsigned int rstart[RPB + 1];
    __shared__ unsigned int rc[RPB];
    __shared__ unsigned int sscan[RPB];
    const int b = blockIdx.x, t = threadIdx.x;
    // thread t owns chunk t's sub-run; two coalesced 1KB bound rows
    const unsigned int s  = matT[(size_t)b * NWG + t];
    const unsigned int e2 = matT[(size_t)(b + 1) * NWG + t];
    const unsigned int base = (unsigned)t * CHUNK;
    const int g   = t >> 5;        // 0..7: 8 groups, 8 rows each
    const int sub = t & 31;        // feature pair; active sub < 24
    const bool act = sub < 24;
    const int row0 = b * RPB;

#define PROC(q)                                                       \
    {                                                                 \
        union { __half h; unsigned short u; } hv;                     \
        hv.u = (unsigned short)((q) >> 17);                           \
        float vv = __half2float(hv.h);                                \
        __half2 e2v = embeds_h2[((q) & 0x1FFFFu) * 24 + sub];         \
        ax = fmaf(vv, __low2float(e2v), ax);                          \
        ay = fmaf(vv, __high2float(e2v), ay);                         \
    }

    if (t < RPB) rc[t] = 0u;
    __syncthreads();
    // pass 1: count rows (each thread serial over its contiguous run)
    for (unsigned int k = s; k < e2; ++k)
        atomicAdd(&rc[(unsigned)buf1[base + k].x >> 17], 1u);
    __syncthreads();
    // scan 64 counts (threads 0..63 active, barriers block-wide)
    if (t < RPB) sscan[t] = rc[t];
    __syncthreads();
    for (int off = 1; off < RPB; off <<= 1) {
        unsigned int u = 0;
        if (t < RPB && t >= off) u = sscan[t - off];
        __syncthreads();
        if (t < RPB && t >= off) sscan[t] += u;
        __syncthreads();
    }
    if (t < RPB) {
        unsigned int pre = (t == 0) ? 0u : sscan[t - 1];
        rstart[t] = pre;
        rc[t] = pre;   // reuse as scatter cursor
    }
    if (t == 0) rstart[RPB] = sscan[RPB - 1];
    __syncthreads();
    const unsigned int cnt = rstart[RPB];

    if (cnt <= CAP) {
        // pass 2: scatter into row-sorted LDS (runs re-read, L2-hot)
        for (unsigned int k = s; k < e2; ++k) {
            int2 cv = buf1[base + k];
            unsigned int pos = atomicAdd(&rc[(unsigned)cv.x >> 17], 1u);
            union { __half h; unsigned short u; } hv;
            hv.h = __float2half_rn(__int_as_float(cv.y));  // val>=0 -> 15 bits
            sedge[pos] = ((unsigned int)hv.u << 17) | ((unsigned)cv.x & 0x1FFFFu);
        }
        __syncthreads();

        for (int rr = g * 8; rr < g * 8 + 8; ++rr) {
            int row = row0 + rr;
            if (row >= N_NODES) break;
            unsigned int j = rstart[rr], end = rstart[rr + 1];
            float ax = 0.f, ay = 0.f;
            for (; j + 8 <= end; j += 8) {
                unsigned int q0 = sedge[j + 0];
                unsigned int q1 = sedge[j + 1];
                unsigned int q2 = sedge[j + 2];
                unsigned int q3 = sedge[j + 3];
                unsigned int q4 = sedge[j + 4];
                unsigned int q5 = sedge[j + 5];
                unsigned int q6 = sedge[j + 6];
                unsigned int q7 = sedge[j + 7];
                if (act) {
                    PROC(q0) PROC(q1) PROC(q2) PROC(q3)
                    PROC(q4) PROC(q5) PROC(q6) PROC(q7)
                }
            }
            for (; j < end; ++j) {
                unsigned int q = sedge[j];
                if (act) PROC(q)
            }
            if (act)
                *(float2*)(out + (size_t)row * D_FEAT + sub * 2) = make_float2(ax, ay);
        }
    } else {
        // capacity-overflow fallback (16-sigma event): filter-scan all runs
        for (int rr = g * 8; rr < g * 8 + 8; ++rr) {
            int row = row0 + rr;
            if (row >= N_NODES) break;
            float ax = 0.f, ay = 0.f;
            for (int i = 0; i < NWG; ++i) {
                unsigned int si = matT[(size_t)b * NWG + i];
                unsigned int ei = matT[(size_t)(b + 1) * NWG + i];
                for (unsigned int k = si; k < ei; ++k) {
                    int2 cv = buf1[(unsigned)i * CHUNK + k];
                    if (((unsigned)cv.x >> 17) == (unsigned)rr && act) {
                        union { __half h; unsigned short u; } hv;
                        hv.h = __float2half_rn(__int_as_float(cv.y));
                        unsigned int q = ((unsigned int)hv.u << 17) | ((unsigned)cv.x & 0x1FFFFu);
                        PROC(q)
                    }
                }
            }
            if (act)
                *(float2*)(out + (size_t)row * D_FEAT + sub * 2) = make_float2(ax, ay);
        }
    }
#undef PROC
}

// ---- fallback (tiny ws): edge-parallel global atomics ----
__global__ __launch_bounds__(256) void zero_out_kernel(float4* __restrict__ out, int n4) {
    int i = blockIdx.x * 256 + threadIdx.x;
    if (i < n4) out[i] = make_float4(0.f, 0.f, 0.f, 0.f);
}
__global__ __launch_bounds__(256) void spmm_atomic_kernel(const int* __restrict__ rows,
                                                          const int* __restrict__ cols,
                                                          const float* __restrict__ vals,
                                                          const float* __restrict__ embeds,
                                                          float* __restrict__ out) {
    long long tid = (long long)blockIdx.x * 256 + threadIdx.x;
    const long long total = (long long)N_EDGES * 12;
    if (tid >= total) return;
    int e = (int)(tid / 12), q = (int)(tid % 12);
    int r = rows[e], c = cols[e];
    float v = vals[e];
    const float4 emb = *(const float4*)(embeds + (long long)c * D_FEAT + q * 4);
    float* o = out + (long long)r * D_FEAT + q * 4;
    atomicAdd(o + 0, v * emb.x);
    atomicAdd(o + 1, v * emb.y);
    atomicAdd(o + 2, v * emb.z);
    atomicAdd(o + 3, v * emb.w);
}

extern "C" void kernel_launch(void* const* d_in, const int* in_sizes, int n_in,
                              void* d_out, int out_size, void* d_ws, size_t ws_size,
                              hipStream_t stream) {
    const int*   rows   = (const int*)d_in[0];
    const int*   cols   = (const int*)d_in[1];
    const float* vals   = (const float*)d_in[2];
    const float* embeds = (const float*)d_in[3];
    float*       out    = (float*)d_out;

    // workspace layout (~24 MB):
    //   matT: MROW*NWG u32 (transposed chunk-local bucket starts) |
    //   buf1: E int2 | embeds_h: N*48 fp16
    unsigned int* matT = (unsigned int*)d_ws;
    size_t mat_bytes  = ((size_t)MROW * NWG * 4 + 15) & ~(size_t)15;
    int2* buf1 = (int2*)((char*)d_ws + mat_bytes);
    __half2* embeds_h2 = (__half2*)((char*)buf1 + (size_t)N_EDGES * 8);
    size_t need = mat_bytes + (size_t)N_EDGES * 8 + (size_t)N_NODES * D_FEAT * 2;

    if (ws_size < need) {
        int n4 = out_size / 4;
        zero_out_kernel<<<(n4 + 255) / 256, 256, 0, stream>>>((float4*)out, n4);
        long long total = (long long)N_EDGES * 12;
        spmm_atomic_kernel<<<(int)((total + 255) / 256), 256, 0, stream>>>(rows, cols, vals, embeds, out);
        return;
    }

    build_convert<<<NWG + CONV_BLK, 512, 0, stream>>>(rows, cols, vals, matT, buf1,
                                                      (const float4*)embeds, embeds_h2);
    finalize_spmm<<<NBUCKETS, 256, 0, stream>>>(matT, buf1, embeds_h2, out);
}